// Round 3
// baseline (814.295 us; speedup 1.0000x reference)
//
#include <hip/hip_runtime.h>
#include <stdint.h>
#include <stddef.h>

#define K_FULL 12544
#define M_ROWS 8192
#define NCLS 81
#define NREG 324
#define NTOT 405
#define NPAD 448          /* 4 n-groups x 7 frags x 16 */
#define OUT0 663552       /* 8192*81 */
#define OUT_TOTAL 3317760 /* 8192*405 */
#define KSPLIT 3136       /* K_FULL/4 */
#define NCHUNK 98         /* KSPLIT/32 */

typedef __bf16 bf16x8 __attribute__((ext_vector_type(8)));
typedef float floatx4 __attribute__((ext_vector_type(4)));

__device__ __forceinline__ uint32_t pack2_bf16(float a, float b) {
  uint32_t ua = __float_as_uint(a);
  uint32_t ub = __float_as_uint(b);
  ua = (ua + 0x7FFFu + ((ua >> 16) & 1u)) >> 16;
  ub = (ub + 0x7FFFu + ((ub >> 16) & 1u)) >> 16;
  return ua | (ub << 16);
}

// ---------------------------------------------------------------------------
// Kernel 1: pack W_cls (81 x K) + W_reg (324 x K) fp32 -> bf16 Wb[448][K].
// Rows 405..447 are zero.
// ---------------------------------------------------------------------------
__global__ void pack_w(const float* __restrict__ Wc, const float* __restrict__ Wr,
                       uint16_t* __restrict__ Wb) {
  const int u = blockIdx.x * blockDim.x + threadIdx.x; // unit of 8 elems
  if (u >= (K_FULL / 8)) return;
  const int row = blockIdx.y; // 0..447
  uint4 v = {0u, 0u, 0u, 0u};
  const float* src = nullptr;
  if (row < NCLS) src = Wc + (size_t)row * K_FULL;
  else if (row < NTOT) src = Wr + (size_t)(row - NCLS) * K_FULL;
  if (src) {
    const float4 f0 = *(const float4*)(src + u * 8);
    const float4 f1 = *(const float4*)(src + u * 8 + 4);
    v.x = pack2_bf16(f0.x, f0.y);
    v.y = pack2_bf16(f0.z, f0.w);
    v.z = pack2_bf16(f1.x, f1.y);
    v.w = pack2_bf16(f1.z, f1.w);
  }
  *(uint4*)(Wb + (size_t)row * K_FULL + u * 8) = v;
}

// ---------------------------------------------------------------------------
// Kernel 2: initialize d_out with the biases (K-split GEMM atomically adds).
// ---------------------------------------------------------------------------
__global__ void bias_init(const float* __restrict__ bc, const float* __restrict__ br,
                          float* __restrict__ out) {
  const int i = blockIdx.x * blockDim.x + threadIdx.x;
  if (i >= OUT_TOTAL) return;
  if (i < OUT0) out[i] = bc[i % NCLS];
  else out[i] = br[(i - OUT0) % NREG];
}

// ---------------------------------------------------------------------------
// Kernel 3: bf16 MFMA GEMM, single-barrier double-buffered B pipeline.
// Grid: 512 = 128 M-tiles (64 rows) x 4 K-splits. bid&3 = split -> per-XCD
//   L2 holds one 2.6 MB B K-quarter.
// Block: 512 thr = 8 waves = 2 m-groups x 4 n-groups. Wave: 2 m-frags x
//   7 n-frags (16x16x32 bf16), each b-frag feeds 2 MFMAs.
// A: global->reg direct (no LDS), next-chunk register prefetch; the 4
//   ng-waves re-read the same 8 KB A-chunk -> served by L1.
// B: LDS double buffer 2 x 28 KB via global_load_lds(16B). DMA(c+1) issued
//   BEFORE compute(c); the barrier at iter c+1 drains it after a full
//   compute phase -> DMA hidden (no naked vmcnt(0) drain).
// ---------------------------------------------------------------------------
__global__ __launch_bounds__(512, 4) void gemm_kernel(
    const float* __restrict__ x, const uint16_t* __restrict__ Wb,
    float* __restrict__ out) {
  __shared__ uint8_t sB[2][28672]; // 2 x (448 rows x 64 B)

  const int tid = threadIdx.x;
  const int lane = tid & 63;
  const int wave = tid >> 6; // 0..7
  const int mg = wave >> 2;  // 0..1
  const int ng = wave & 3;   // 0..3

  const int mt = blockIdx.x >> 2; // 0..127
  const int ks = blockIdx.x & 3;  // 0..3
  const int rowBase = mt * 64;
  const int k0 = ks * KSPLIT;

  const int i15 = lane & 15;
  const int q = lane >> 4; // 0..3 (k-quad)

  floatx4 acc[2][7];
  const floatx4 zero = {0.0f, 0.0f, 0.0f, 0.0f};
#pragma unroll
  for (int i = 0; i < 2; ++i)
#pragma unroll
    for (int j = 0; j < 7; ++j) acc[i][j] = zero;

  // ---- A geometry: lane reads 8 consecutive fp32 (k = q*8..q*8+7) of two
  //      rows (mg*32 + i15, +16). Advances 32 per chunk.
  const float* gA0 = x + (size_t)(rowBase + mg * 32 + i15) * K_FULL + k0 + q * 8;
  const float* gA1 = gA0 + (size_t)16 * K_FULL;

  // ---- B DMA geometry: per instruction 16 rows x 64 B (1 KB). Lane: row
  //      u*16 + (lane>>2), 16B unit (lane&3). 28 instructions per chunk,
  //      wave w handles u = w, w+8, w+16, w+24 (<28).
  const uint16_t* gB = Wb + (size_t)(lane >> 2) * K_FULL + k0 + (lane & 3) * 8;

  // ---- prologue: DMA chunk 0 into buf 0, prefetch A chunk 0 ----
#pragma unroll
  for (int u = 0; u < 4; ++u) {
    const int uu = wave + u * 8;
    if (uu < 28)
      __builtin_amdgcn_global_load_lds(
          (const __attribute__((address_space(1))) void*)(gB + (size_t)uu * 16 * K_FULL),
          (__attribute__((address_space(3))) void*)(&sB[0][uu * 1024]), 16, 0, 0);
  }
  float4 pf0 = *(const float4*)gA0;
  float4 pf1 = *(const float4*)(gA0 + 4);
  float4 pf2 = *(const float4*)gA1;
  float4 pf3 = *(const float4*)(gA1 + 4);

  for (int c = 0; c < NCHUNK; ++c) {
    const int cur = c & 1;
    const int cn = (c + 1 < NCHUNK) ? (c + 1) : (NCHUNK - 1); // clamp (dead buf)

    // One barrier per chunk: (a) all waves done computing on buf[cur^1]
    // -> free for DMA(c+1); (b) vmcnt(0) drain completes DMA(c) into
    // buf[cur], which has been in flight for the whole previous compute.
    __syncthreads();

    // ---- issue DMA(c+1) into the just-freed buffer ----
#pragma unroll
    for (int u = 0; u < 4; ++u) {
      const int uu = wave + u * 8;
      if (uu < 28)
        __builtin_amdgcn_global_load_lds(
            (const __attribute__((address_space(1))) void*)(gB + (size_t)uu * 16 * K_FULL + cn * 32),
            (__attribute__((address_space(3))) void*)(&sB[cur ^ 1][uu * 1024]), 16, 0, 0);
    }

    // ---- convert current A prefetch regs -> bf16 fragments ----
    bf16x8 a0, a1;
    a0[0] = (__bf16)pf0.x; a0[1] = (__bf16)pf0.y; a0[2] = (__bf16)pf0.z; a0[3] = (__bf16)pf0.w;
    a0[4] = (__bf16)pf1.x; a0[5] = (__bf16)pf1.y; a0[6] = (__bf16)pf1.z; a0[7] = (__bf16)pf1.w;
    a1[0] = (__bf16)pf2.x; a1[1] = (__bf16)pf2.y; a1[2] = (__bf16)pf2.z; a1[3] = (__bf16)pf2.w;
    a1[4] = (__bf16)pf3.x; a1[5] = (__bf16)pf3.y; a1[6] = (__bf16)pf3.z; a1[7] = (__bf16)pf3.w;

    // ---- prefetch next A chunk (lands during compute) ----
    {
      const float* nA0 = gA0 + cn * 32;
      const float* nA1 = gA1 + cn * 32;
      pf0 = *(const float4*)nA0;
      pf1 = *(const float4*)(nA0 + 4);
      pf2 = *(const float4*)nA1;
      pf3 = *(const float4*)(nA1 + 4);
    }

    // ---- compute chunk c from buf[cur] ----
    const uint8_t* bbase = &sB[cur][0] + (ng * 112 + i15) * 64 + q * 16;
#pragma unroll
    for (int f = 0; f < 7; ++f) {
      const bf16x8 b = *(const bf16x8*)(bbase + f * 1024); // 16 rows * 64 B
      acc[0][f] = __builtin_amdgcn_mfma_f32_16x16x32_bf16(a0, b, acc[0][f], 0, 0, 0);
      acc[1][f] = __builtin_amdgcn_mfma_f32_16x16x32_bf16(a1, b, acc[1][f], 0, 0, 0);
    }
  }

  // ---- epilogue: atomic-add partials into split cls/reg outputs ----
  // C/D layout: col = lane&15, row = (lane>>4)*4 + reg  [m89/m91]
#pragma unroll
  for (int fm = 0; fm < 2; ++fm) {
    const int r0 = rowBase + mg * 32 + fm * 16 + q * 4;
#pragma unroll
    for (int f = 0; f < 7; ++f) {
      const int col = ng * 112 + f * 16 + i15;
      if (col < NCLS) {
        float* dst = out + (size_t)r0 * NCLS + col;
#pragma unroll
        for (int r = 0; r < 4; ++r)
          unsafeAtomicAdd(dst + (size_t)r * NCLS, acc[fm][f][r]);
      } else if (col < NTOT) {
        float* dst = out + OUT0 + (size_t)r0 * NREG + (col - NCLS);
#pragma unroll
        for (int r = 0; r < 4; ++r)
          unsafeAtomicAdd(dst + (size_t)r * NREG, acc[fm][f][r]);
      }
    }
  }
}

extern "C" void kernel_launch(void* const* d_in, const int* in_sizes, int n_in,
                              void* d_out, int out_size, void* d_ws, size_t ws_size,
                              hipStream_t stream) {
  const float* x = (const float*)d_in[0];
  const float* Wc = (const float*)d_in[1];
  const float* bc = (const float*)d_in[2];
  const float* Wr = (const float*)d_in[3];
  const float* br = (const float*)d_in[4];
  float* out = (float*)d_out;
  uint16_t* Wb = (uint16_t*)d_ws; // 448*12544*2 = 11,239,424 B

  pack_w<<<dim3(7, NPAD), dim3(256), 0, stream>>>(Wc, Wr, Wb);
  bias_init<<<dim3((OUT_TOTAL + 255) / 256), dim3(256), 0, stream>>>(bc, br, out);
  gemm_kernel<<<dim3(512), dim3(512), 0, stream>>>(x, Wb, out);
}